// Round 1
// 195.185 us; speedup vs baseline: 1.1615x; 1.1615x over previous
//
#include <hip/hip_runtime.h>
#include <math.h>

#define AB 128   // A == B == 128
#define NN 64    // N
#define HD 1024  // H

// fp32 -> f16 hi/lo split scales. Z ~ N(0,1) -> x256 keeps lo normal;
// F entries ~1e-2 -> x64. S' = FXs*Zs^T ~ O(300): hi fine, lo normal.
// out = acc * gamma * 2^-20.
#define SFZ 256.0f
#define SFF 64.0f
#define DESCALE (1.0f / 1048576.0f)  // 2^-(8+6+6)

typedef _Float16 half8 __attribute__((ext_vector_type(8)));
typedef float f32x4 __attribute__((ext_vector_type(4)));
typedef unsigned u32x4 __attribute__((ext_vector_type(4)));

// ---------------------------------------------------------------------------
// ws layout (halves):
//   [0,     8192)   FXhi[m][b]   row-major, scaled by 64
//   [8192,  16384)  FXlo[m][b]
//   [16384, 24576)  FYhi[n][a]
//   [24576, 32768)  FYlo[n][a]
//   float at half-offset 32768 (byte 65536): gamma * 2^-20
// ---------------------------------------------------------------------------

__device__ __forceinline__ float wave_reduce(float v) {
  v += __shfl_down(v, 32);
  v += __shfl_down(v, 16);
  v += __shfl_down(v, 8);
  v += __shfl_down(v, 4);
  v += __shfl_down(v, 2);
  v += __shfl_down(v, 1);
  return v;  // valid in lane 0
}

__global__ __launch_bounds__(1024) void fb_setup(
    const float* __restrict__ h, const float* __restrict__ Ww,
    const float* __restrict__ Wb, void* __restrict__ wsv) {
  __shared__ float redp[16][5];
  __shared__ float reds[16][2];
  __shared__ float sc[5];
  __shared__ float ssum[2];
  const int tid = threadIdx.x;
  const int lane = tid & 63;
  const int wv = tid >> 6;

  // ---- params[j] = dot(h[0,:], W[j,:]) + b[j] ----
  const float hv = h[tid];
  float p[5];
#pragma unroll
  for (int j = 0; j < 5; ++j) p[j] = hv * Ww[j * HD + tid];
#pragma unroll
  for (int j = 0; j < 5; ++j) {
    float r = wave_reduce(p[j]);
    if (lane == 0) redp[wv][j] = r;
  }
  __syncthreads();
  if (tid < 5) {
    float s = Wb[tid];
#pragma unroll
    for (int w = 0; w < 16; ++w) s += redp[w][tid];
    sc[tid] = s;
  }
  __syncthreads();

  const float gt_X = sc[0], gt_Y = sc[1], log_var = sc[2], log_dt = sc[3];
  const float var = expf(log_var + 1e-8f);
  const float g_X = (129.0f * (gt_X + 1.0f)) / 2.0f;
  const float g_Y = (129.0f * (gt_Y + 1.0f)) / 2.0f;
  const float d = (expf(log_dt) * 127.0f) / 63.0f;
  const float twovar = 2.0f * var;

  float fyv[8], fxv[8];
  float sY = 0.f, sX = 0.f;
#pragma unroll
  for (int c = 0; c < 8; ++c) {
    const int idx = tid + 1024 * c;
    const int n = idx >> 7;
    const int col = idx & 127;
    const float idxn = (float)n - 32.5f;
    const float muX = g_X + idxn * d;
    const float muY = g_Y + idxn * d;
    const float dx = (float)col - muX;
    const float dy = (float)col - muY;
    const float fx = expf(-(dx * dx) / twovar);
    const float fy = expf(-(dy * dy) / twovar);
    fyv[c] = fy;
    fxv[c] = fx;
    sY += fy;
    sX += fx;
  }
  {
    float rY = wave_reduce(sY);
    float rX = wave_reduce(sX);
    if (lane == 0) { reds[wv][0] = rY; reds[wv][1] = rX; }
  }
  __syncthreads();
  if (tid < 2) {
    float s = 0.f;
#pragma unroll
    for (int w = 0; w < 16; ++w) s += reds[w][tid];
    ssum[tid] = s;
  }
  __syncthreads();
  const float invY = 1.0f / ssum[0];
  const float invX = 1.0f / ssum[1];

  _Float16* FXhi = (_Float16*)wsv;
  _Float16* FXlo = FXhi + NN * AB;
  _Float16* FYhi = FXhi + 2 * NN * AB;
  _Float16* FYlo = FXhi + 3 * NN * AB;

#pragma unroll
  for (int c = 0; c < 8; ++c) {
    const int idx = tid + 1024 * c;  // == n*128 + col, row-major
    const float vy = fyv[c] * invY * SFF;
    const float vx = fxv[c] * invX * SFF;
    const _Float16 yh = (_Float16)vy;
    const _Float16 xh2 = (_Float16)vx;
    FYhi[idx] = yh;
    FYlo[idx] = (_Float16)(vy - (float)yh);
    FXhi[idx] = xh2;
    FXlo[idx] = (_Float16)(vx - (float)xh2);
  }
  if (tid == 0) ((float*)wsv)[2 * NN * AB] = expf(sc[4]) * DESCALE;
}

// ---------------------------------------------------------------------------
// fb_filt: one block (256 thr = 4 waves) per image.
// Stage 1: S'(64x128) = FXs(64x128) @ Zs^T  -- contraction over b = Z's
//   column index, so the MFMA B-fragment of Z is 8 *consecutive* fp32 of a
//   Z row per lane: direct global float4 loads, convert in-register, no LDS.
//   Wave w owns a-strip [32w,32w+32) (2 N-tiles), all 4 M-tiles.
// S' -> LDS packed (hi16|lo16) per element, [64][140] u32 (writes 2-way =
//   free; b128 reads exactly 8 words/bank = conflict-free).
// Stage 2: out(64x64) = FYs(64x128) @ S'^T; D rows = n, cols = m, so the
//   epilogue stores dwords covering full 64B lines in out[n][m] order.
// 3-product f16 emulation per GEMM: Ahi*Bhi + Ahi*Blo + Alo*Bhi (fp32 acc).
// ---------------------------------------------------------------------------
__device__ __forceinline__ void split8(const f32x4 z0, const f32x4 z1,
                                       float s, half8& hi, half8& lo) {
#pragma unroll
  for (int e = 0; e < 8; ++e) {
    const float q = (e < 4 ? z0[e] : z1[e - 4]) * s;
    const _Float16 hh = (_Float16)q;
    hi[e] = hh;
    lo[e] = (_Float16)(q - (float)hh);
  }
}

__global__ __launch_bounds__(256) void fb_filt(
    const float* __restrict__ x, const float* __restrict__ xh,
    const void* __restrict__ wsv, float* __restrict__ out) {
  __shared__ unsigned S_lds[NN * 140];  // 35840 B -> 4 blocks/CU

  const int tid = threadIdx.x;
  const int lane = tid & 63;
  const int wv = tid >> 6;   // 0..3
  const int l15 = lane & 15;
  const int h4 = lane >> 4;  // 0..3
  const int bid = blockIdx.x;
  const int img = bid >> 1;
  const int which = bid & 1;
  const float* __restrict__ Z = (which ? xh : x) + (size_t)img * (AB * AB);
  const _Float16* __restrict__ FXhi = (const _Float16*)wsv;
  const _Float16* __restrict__ FXlo = FXhi + NN * AB;
  const _Float16* __restrict__ FYhi = FXhi + 2 * NN * AB;
  const _Float16* __restrict__ FYlo = FXhi + 3 * NN * AB;

  f32x4 acc[4][2];  // [m-tile][n-tile within wave strip]
#pragma unroll
  for (int mt = 0; mt < 4; ++mt)
#pragma unroll
    for (int j = 0; j < 2; ++j) acc[mt][j] = {0.f, 0.f, 0.f, 0.f};

  // ---- Stage 1 ----
#pragma unroll
  for (int ks = 0; ks < 4; ++ks) {
    half8 bhi[2], blo[2];
#pragma unroll
    for (int j = 0; j < 2; ++j) {
      // B[k=b][col=a]: lane holds Z[a = 32w+16j+l15][b = 32ks+8h4 .. +7]
      const float* zp = Z + (32 * wv + 16 * j + l15) * AB + 32 * ks + 8 * h4;
      const f32x4 z0 = *(const f32x4*)zp;
      const f32x4 z1 = *(const f32x4*)(zp + 4);
      split8(z0, z1, SFZ, bhi[j], blo[j]);
    }
#pragma unroll
    for (int mt = 0; mt < 4; ++mt) {
      // A[row=m][k=b]: lane holds FXs[16mt+l15][32ks+8h4 .. +7]
      const int off = (16 * mt + l15) * AB + 32 * ks + 8 * h4;
      const half8 ahi = *(const half8*)(FXhi + off);
      const half8 alo = *(const half8*)(FXlo + off);
#pragma unroll
      for (int j = 0; j < 2; ++j) {
        acc[mt][j] = __builtin_amdgcn_mfma_f32_16x16x32_f16(ahi, bhi[j], acc[mt][j], 0, 0, 0);
        acc[mt][j] = __builtin_amdgcn_mfma_f32_16x16x32_f16(ahi, blo[j], acc[mt][j], 0, 0, 0);
        acc[mt][j] = __builtin_amdgcn_mfma_f32_16x16x32_f16(alo, bhi[j], acc[mt][j], 0, 0, 0);
      }
    }
  }

  // ---- S' -> LDS, split + packed (hi16 | lo16) ----
#pragma unroll
  for (int mt = 0; mt < 4; ++mt) {
#pragma unroll
    for (int j = 0; j < 2; ++j) {
      const int a = 32 * wv + 16 * j + l15;
#pragma unroll
      for (int r = 0; r < 4; ++r) {
        const float v = acc[mt][j][r];
        const _Float16 hh = (_Float16)v;
        const _Float16 ll = (_Float16)(v - (float)hh);
        const unsigned wpk =
            ((unsigned)__builtin_bit_cast(unsigned short, hh) << 16) |
            (unsigned)__builtin_bit_cast(unsigned short, ll);
        S_lds[(16 * mt + 4 * h4 + r) * 140 + a] = wpk;
      }
    }
  }
  __syncthreads();

  // ---- Stage 2 ----
  f32x4 acc2[4];
#pragma unroll
  for (int mt = 0; mt < 4; ++mt) acc2[mt] = {0.f, 0.f, 0.f, 0.f};

#pragma unroll
  for (int ks = 0; ks < 4; ++ks) {
    const int aoff = 32 * ks + 8 * h4;
    // A[row=n][k=a]: lane holds FYs[16wv+l15][aoff .. +7]
    const int foff = (16 * wv + l15) * AB + aoff;
    const half8 ahi = *(const half8*)(FYhi + foff);
    const half8 alo = *(const half8*)(FYlo + foff);
#pragma unroll
    for (int mt = 0; mt < 4; ++mt) {
      // B[k=a][col=m]: lane holds S'[m = 16mt+l15][aoff .. +7]
      const unsigned* sp = &S_lds[(16 * mt + l15) * 140 + aoff];
      const u32x4 w0 = *(const u32x4*)sp;
      const u32x4 w1 = *(const u32x4*)(sp + 4);
      u32x4 bhu, blu;
      bhu.x = __builtin_amdgcn_perm(w0.y, w0.x, 0x07060302u);
      blu.x = __builtin_amdgcn_perm(w0.y, w0.x, 0x05040100u);
      bhu.y = __builtin_amdgcn_perm(w0.w, w0.z, 0x07060302u);
      blu.y = __builtin_amdgcn_perm(w0.w, w0.z, 0x05040100u);
      bhu.z = __builtin_amdgcn_perm(w1.y, w1.x, 0x07060302u);
      blu.z = __builtin_amdgcn_perm(w1.y, w1.x, 0x05040100u);
      bhu.w = __builtin_amdgcn_perm(w1.w, w1.z, 0x07060302u);
      blu.w = __builtin_amdgcn_perm(w1.w, w1.z, 0x05040100u);
      const half8 bh = __builtin_bit_cast(half8, bhu);
      const half8 bl = __builtin_bit_cast(half8, blu);
      acc2[mt] = __builtin_amdgcn_mfma_f32_16x16x32_f16(ahi, bh, acc2[mt], 0, 0, 0);
      acc2[mt] = __builtin_amdgcn_mfma_f32_16x16x32_f16(ahi, bl, acc2[mt], 0, 0, 0);
      acc2[mt] = __builtin_amdgcn_mfma_f32_16x16x32_f16(alo, bh, acc2[mt], 0, 0, 0);
    }
  }

  // ---- Epilogue: D[row = n = 16wv+4h4+r][col = m = 16mt+l15] ----
  const float gamma_eff = ((const float*)wsv)[2 * NN * AB];
  float* __restrict__ ob = out + (size_t)img * 8192 + which * 4096;
#pragma unroll
  for (int mt = 0; mt < 4; ++mt) {
#pragma unroll
    for (int r = 0; r < 4; ++r) {
      ob[(16 * wv + 4 * h4 + r) * 64 + 16 * mt + l15] = acc2[mt][r] * gamma_eff;
    }
  }
}

extern "C" void kernel_launch(void* const* d_in, const int* in_sizes, int n_in,
                              void* d_out, int out_size, void* d_ws, size_t ws_size,
                              hipStream_t stream) {
  const float* x = (const float*)d_in[0];
  const float* xh = (const float*)d_in[1];
  const float* h = (const float*)d_in[2];
  const float* Ww = (const float*)d_in[3];
  const float* Wb = (const float*)d_in[4];
  float* outp = (float*)d_out;

  fb_setup<<<1, 1024, 0, stream>>>(h, Ww, Wb, d_ws);
  fb_filt<<<2048, 256, 0, stream>>>(x, xh, (const void*)d_ws, outp);
}